// Round 8
// baseline (204.286 us; speedup 1.0000x reference)
//
#include <hip/hip_runtime.h>
#include <hip/hip_bf16.h>
#include <hip/hip_fp8.h>
#include <stdint.h>

#define NN 50000
#define NE 800000
#define F 128
#define NCLS 16
#define NB 196          // ceil(50000/256) buckets
#define BCAP 5120       // per-bucket capacity: mean 4096 + 16 sigma
#define PA_EPT 16       // edges per thread in pass_a part
#define PW_BLKS 192     // 6 matrices x 32 blocks
#define CV_BLKS 6250    // NN*32/256

typedef __attribute__((ext_vector_type(8))) short short8;
typedef __attribute__((ext_vector_type(4))) float f32x4;
typedef __attribute__((ext_vector_type(2))) float f32x2;
typedef __attribute__((ext_vector_type(4))) unsigned int uint4v;

// ---- ws byte offsets (ws_size ~256 MiB, plenty) ----
#define OB_COLSUM    0u          // float[128]
#define OB_BCUR      512u        // int[196] (fill counters, memset 0)
#define OB_ROWSTART  4096u       // int[50001]
#define OB_INVDEG    204800u     // float[50000]
#define OB_PAIRS     409600u     // u32[196*5120]
#define OB_SRCS16    4423680u    // u16[800000]
#define OB_WT        6023680u    // bf16 6*16384 (layout L)
#define OB_XB        6220800u    // bf16 [NN][128] layout L (doubles as HB2)
#define OB_HB1       19020800u   // bf16 [NN][128] layout L
#define OB_X8        31820800u   // fp8 [NN][128] row-major (doubles as F8B)
#define OB_F8A       38220800u   // fp8 [NN][128] row-major
#define OB_NB        44620800u   // bf16 [NN][128] layout L   ends 57420800

// ---- swizzled bf16 feature layout L ----
// element (row,k) at byte: row*256 + 16*(chunk(k) ^ (row&15)) + inchunk(k)
// chunk(k) = (k>>5)*4 | ((k>>2)&3); inchunk = ((k>>4)&1)*8 + (k&3)*2
__device__ __forceinline__ uint32_t swz_off(uint32_t row, uint32_t k) {
    uint32_t c = ((k >> 5) << 2) | ((k >> 2) & 3u);
    uint32_t b = (((k >> 4) & 1u) << 3) | ((k & 3u) << 1);
    return (row << 8) + (((c ^ (row & 15u)) << 4) | b);
}

__device__ __forceinline__ uint32_t pack_bf2(float a, float b) {
    __hip_bfloat16 l = __float2bfloat16(a), h = __float2bfloat16(b);
    return ((uint32_t)(*(uint16_t*)&h) << 16) | (uint32_t)(*(uint16_t*)&l);
}

__device__ __forceinline__ uint8_t f32_to_fp8(float v) {
#if __has_builtin(__builtin_amdgcn_cvt_pk_fp8_f32)
    return (uint8_t)(__builtin_amdgcn_cvt_pk_fp8_f32(v, 0.f, 0, false) & 0xff);
#else
    __hip_fp8_e4m3 t(v);
    return t.__x;
#endif
}

__device__ __forceinline__ uint32_t f32x4_to_fp8x4(float a, float b, float c, float d) {
#if __has_builtin(__builtin_amdgcn_cvt_pk_fp8_f32)
    int r = __builtin_amdgcn_cvt_pk_fp8_f32(a, b, 0, false);
    r = __builtin_amdgcn_cvt_pk_fp8_f32(c, d, r, true);
    return (uint32_t)r;
#else
    __hip_fp8_e4m3 ta(a), tb(b), tc(c), td(d);
    return (uint32_t)ta.__x | ((uint32_t)tb.__x << 8) | ((uint32_t)tc.__x << 16) | ((uint32_t)td.__x << 24);
#endif
}

// accumulate 4 fp8 (one dword) into two packed-f32 accumulators
__device__ __forceinline__ void acc4(uint32_t d, f32x2& p0, f32x2& p1) {
#if __has_builtin(__builtin_amdgcn_cvt_pk_f32_fp8)
    p0 += __builtin_amdgcn_cvt_pk_f32_fp8((int)d, false);
    p1 += __builtin_amdgcn_cvt_pk_f32_fp8((int)d, true);
#else
    __hip_fp8_e4m3 t0, t1, t2, t3;
    t0.__x = (uint8_t)(d & 0xff); t1.__x = (uint8_t)((d >> 8) & 0xff);
    t2.__x = (uint8_t)((d >> 16) & 0xff); t3.__x = (uint8_t)((d >> 24) & 0xff);
    p0.x += (float)t0; p0.y += (float)t1; p1.x += (float)t2; p1.y += (float)t3;
#endif
}

// async global->LDS, 16B per lane (dest must be wave-uniform base + lane*16)
__device__ __forceinline__ void gload16(const void* g, void* l) {
    __builtin_amdgcn_global_load_lds(
        (const __attribute__((address_space(1))) unsigned int*)g,
        (__attribute__((address_space(3))) unsigned int*)l, 16, 0, 0);
}

// ====== fused prep: pass_a (196) | prep_w (192) | convert_x2 (6250) ======
__global__ __launch_bounds__(256) void fused_prep(
        const float* __restrict__ x, uint8_t* __restrict__ xb, uint8_t* __restrict__ x8,
        const float* __restrict__ w0, const float* __restrict__ w1,
        const float* __restrict__ w2, const float* __restrict__ w3,
        const float* __restrict__ w4, const float* __restrict__ w5,
        uint8_t* __restrict__ wt,
        const int* __restrict__ src, const int* __restrict__ dst,
        int* __restrict__ bcur, uint32_t* __restrict__ pairs) {
    __shared__ int cnt[NB];
    __shared__ int base_s[NB];
    int bid = blockIdx.x;
    int t = threadIdx.x;

    if (bid < NB) {
        // ---- pass A: LDS-aggregated scatter into fixed-capacity bucket streams
        for (int i = t; i < NB; i += 256) cnt[i] = 0;
        __syncthreads();
        uint32_t pk[PA_EPT];
        int bk[PA_EPT];
        int e0 = bid * (256 * PA_EPT) + t;
#pragma unroll
        for (int j = 0; j < PA_EPT; ++j) {
            int e = e0 + j * 256;
            if (e < NE) {
                int sv = src[e], dv = dst[e];
                bk[j] = dv >> 8;
                pk[j] = (uint32_t)sv | (((uint32_t)dv & 255u) << 16);
                atomicAdd(&cnt[bk[j]], 1);
            } else bk[j] = -1;
        }
        __syncthreads();
        for (int i = t; i < NB; i += 256) {
            if (cnt[i] > 0) base_s[i] = i * BCAP + atomicAdd(&bcur[i], cnt[i]);
            cnt[i] = 0;   // reuse as local cursor
        }
        __syncthreads();
#pragma unroll
        for (int j = 0; j < PA_EPT; ++j) {
            if (bk[j] >= 0) {
                int pos = base_s[bk[j]] + atomicAdd(&cnt[bk[j]], 1);
                pairs[pos] = pk[j];
            }
        }
        return;
    }
    bid -= NB;
    if (bid < PW_BLKS) {
        // ---- prep_w: Wt[n][k] = W[k][n], layout L on (n,k)
        int m = bid >> 5;
        const float* w = m == 0 ? w0 : m == 1 ? w1 : m == 2 ? w2 : m == 3 ? w3 : m == 4 ? w4 : w5;
        int tt = (bid & 31) * 256 + t;          // 8192 pair-slots
        int n = tt >> 6;
        int k0 = (tt & 63) << 1;
        uint32_t pk = pack_bf2(w[k0 * F + n], w[(k0 + 1) * F + n]);
        *(uint32_t*)(wt + (uint32_t)m * 32768u + swz_off((uint32_t)n, (uint32_t)k0)) = pk;
        return;
    }
    bid -= PW_BLKS;
    // ---- convert x to bf16 layout L + fp8 row-major copy
    int tt = bid * 256 + t;                     // NN*32 quad-slots
    uint32_t row = (uint32_t)tt >> 5;
    uint32_t q = (uint32_t)tt & 31u;            // 4-k group
    float4 v = *(const float4*)(x + row * F + q * 4);
    uint32_t c = ((q >> 3) << 2) | (q & 3u);
    uint32_t hi = (q >> 2) & 1u;
    uint2 pk;
    pk.x = pack_bf2(v.x, v.y);
    pk.y = pack_bf2(v.z, v.w);
    *(uint2*)(xb + (row << 8) + (((c ^ (row & 15u)) << 4) | (hi << 3))) = pk;
    *(uint32_t*)(x8 + row * 128u + q * 4u) = f32x4_to_fp8x4(v.x, v.y, v.z, v.w);
}

// ====== pass B: per-bucket count/scan (+inline bucket-base scan) ======
__global__ __launch_bounds__(256) void pass_b(const uint32_t* __restrict__ pairs,
                                              const int* __restrict__ bcur,   // fills
                                              int* __restrict__ row_start,
                                              float* __restrict__ inv_deg,
                                              unsigned short* __restrict__ srcs) {
    __shared__ int sarr[256];
    __shared__ int cnt[256];
    __shared__ int cur[256];
    int b = blockIdx.x, t = threadIdx.x;
    // scan all bucket fills (redundant per block, cheap)
    sarr[t] = (t < NB) ? bcur[t] : 0;
    __syncthreads();
    for (int off = 1; off < 256; off <<= 1) {
        int u = (t >= off) ? sarr[t - off] : 0;
        __syncthreads();
        sarr[t] += u;
        __syncthreads();
    }
    int fill = bcur[b];
    int out0 = sarr[b] - fill;   // exclusive prefix
    int in0 = b * BCAP;
    cnt[t] = 0;
    __syncthreads();
    for (int i = t; i < fill; i += 256)
        atomicAdd(&cnt[pairs[in0 + i] >> 16], 1);
    __syncthreads();
    int v = cnt[t];
    sarr[t] = v;
    __syncthreads();
    for (int off = 1; off < 256; off <<= 1) {
        int u = (t >= off) ? sarr[t - off] : 0;
        __syncthreads();
        sarr[t] += u;
        __syncthreads();
    }
    int excl = sarr[t] - v;
    cur[t] = out0 + excl;
    int row = (b << 8) + t;
    if (row < NN) {
        row_start[row] = out0 + excl;
        inv_deg[row] = 1.0f / (float)(v > 1 ? v : 1);
    }
    if (b == 0 && t == 0) row_start[NN] = NE;
    __syncthreads();
    for (int i = t; i < fill; i += 256) {
        uint32_t p = pairs[in0 + i];
        int pos = atomicAdd(&cur[p >> 16], 1);
        srcs[pos] = (unsigned short)(p & 0xffffu);
    }
}

// ====== aggregate: wave/node, 8 lanes x dwordx4 per row -> 8 edges/instr ======
__global__ __launch_bounds__(256) void aggregate_f8(
        const uint8_t* __restrict__ hf8, const int* __restrict__ row_start,
        const unsigned short* __restrict__ srcs, const float* __restrict__ inv_deg,
        uint8_t* __restrict__ nb) {
    int node = blockIdx.x * 4 + (threadIdx.x >> 6);
    int l = threadIdx.x & 63;
    int g = l >> 3;                          // edge slot 0..7
    uint32_t m = (uint32_t)(l & 7);          // feats [16m, 16m+16)
    const uint8_t* base = hf8 + m * 16u;
    int e0 = row_start[node], e1 = row_start[node + 1];
    f32x2 a[8];
#pragma unroll
    for (int i = 0; i < 8; ++i) { a[i].x = 0.f; a[i].y = 0.f; }

    int e = e0;
    for (; e + 16 <= e1; e += 16) {          // 16 edges in flight per wave
        uint32_t sa = srcs[e + g];
        uint32_t sb = srcs[e + 8 + g];
        uint4 da = *(const uint4*)(base + ((uint32_t)sa << 7));
        uint4 db = *(const uint4*)(base + ((uint32_t)sb << 7));
        acc4(da.x, a[0], a[1]); acc4(da.y, a[2], a[3]);
        acc4(da.z, a[4], a[5]); acc4(da.w, a[6], a[7]);
        acc4(db.x, a[0], a[1]); acc4(db.y, a[2], a[3]);
        acc4(db.z, a[4], a[5]); acc4(db.w, a[6], a[7]);
    }
    if (e + 8 <= e1) {
        uint32_t sa = srcs[e + g];
        uint4 da = *(const uint4*)(base + ((uint32_t)sa << 7));
        acc4(da.x, a[0], a[1]); acc4(da.y, a[2], a[3]);
        acc4(da.z, a[4], a[5]); acc4(da.w, a[6], a[7]);
        e += 8;
    }
    if (e + g < e1) {                        // predicated 0..7-edge tail
        uint32_t sa = srcs[e + g];
        uint4 da = *(const uint4*)(base + ((uint32_t)sa << 7));
        acc4(da.x, a[0], a[1]); acc4(da.y, a[2], a[3]);
        acc4(da.z, a[4], a[5]); acc4(da.w, a[6], a[7]);
    }
    // combine 8 edge groups: xor 8, 16, 32
#pragma unroll
    for (int d = 8; d < 64; d <<= 1) {
#pragma unroll
        for (int i = 0; i < 8; ++i) {
            a[i].x += __shfl_xor(a[i].x, d);
            a[i].y += __shfl_xor(a[i].y, d);
        }
    }
    if (g == 0) {
        float idg = inv_deg[node];
        uint32_t rx = (uint32_t)node & 15u;
        char* rowp = (char*)nb + ((uint32_t)node << 8);
        uint32_t bh = (m & 1u) << 3;
#pragma unroll
        for (int jj = 0; jj < 4; ++jj) {
            uint32_t c = ((m >> 1) << 2) | (uint32_t)jj;
            uint2 w;
            w.x = pack_bf2(a[2 * jj].x * idg, a[2 * jj].y * idg);
            w.y = pack_bf2(a[2 * jj + 1].x * idg, a[2 * jj + 1].y * idg);
            *(uint2*)(rowp + (((c ^ rx) << 4) | bh)) = w;
        }
    }
}

// ====== MFMA GEMM: hout = relu(As@Ws + An@Wn + b); f8 mirror + opt colsum ======
__global__ __launch_bounds__(256) void gemm_mfma(
        const uint8_t* __restrict__ a_self, const uint8_t* __restrict__ a_neigh,
        const uint8_t* __restrict__ wt_self, const uint8_t* __restrict__ wt_neigh,
        const float* __restrict__ bias, uint8_t* __restrict__ hout,
        uint8_t* hout_f8, float* colsum) {
    __shared__ uint4v As4[1024];   // 16 KB
    __shared__ uint4v Ws4[2048];   // 32 KB
    __shared__ float cs[128];
    int tid = threadIdx.x;
    int lane = tid & 63, wave = tid >> 6;
    int rl = lane & 15, g = lane >> 4;
    int row0 = blockIdx.x * 64;

    f32x4 acc[8];
    f32x4 z = {0.f, 0.f, 0.f, 0.f};
#pragma unroll
    for (int nt = 0; nt < 8; ++nt) acc[nt] = z;

    const char* AsB = (const char*)As4;
    const char* WsB = (const char*)Ws4;

#pragma unroll
    for (int pass = 0; pass < 2; ++pass) {
        if (pass) __syncthreads();
        const uint4v* ga = (const uint4v*)((pass ? a_neigh : a_self) + (size_t)row0 * 256);
        const uint4v* gw = (const uint4v*)(pass ? wt_neigh : wt_self);
#pragma unroll
        for (int i = 0; i < 4; ++i) gload16(&ga[tid + i * 256], &As4[tid + i * 256]);
#pragma unroll
        for (int i = 0; i < 8; ++i) gload16(&gw[tid + i * 256], &Ws4[tid + i * 256]);
        __syncthreads();
#pragma unroll
        for (int ks = 0; ks < 4; ++ks) {
            int chunk = ((ks << 2) | g) ^ rl;
            short8 a = *(const short8*)(AsB + ((wave * 16 + rl) << 8) + (chunk << 4));
#pragma unroll
            for (int nt = 0; nt < 8; ++nt) {
                short8 bb = *(const short8*)(WsB + ((nt * 16 + rl) << 8) + (chunk << 4));
                acc[nt] = __builtin_amdgcn_mfma_f32_16x16x32_bf16(a, bb, acc[nt], 0, 0, 0);
            }
        }
    }

    bool doCol = (colsum != nullptr);
    bool doF8 = (hout_f8 != nullptr);
    if (doCol) {
        if (tid < 128) cs[tid] = 0.f;
        __syncthreads();
    }
#pragma unroll
    for (int nt = 0; nt < 8; ++nt) {
        int col = nt * 16 + rl;
        float bv = bias[col];
        float rsum = 0.f;
#pragma unroll
        for (int i = 0; i < 4; ++i) {
            int row = row0 + wave * 16 + g * 4 + i;
            if (row < NN) {
                float v = fmaxf(acc[nt][i] + bv, 0.f);
                rsum += v;
                *(__hip_bfloat16*)(hout + swz_off((uint32_t)row, (uint32_t)col)) =
                    __float2bfloat16(v);
                if (doF8) hout_f8[(uint32_t)row * 128u + (uint32_t)col] = f32_to_fp8(v);
            }
        }
        if (doCol) atomicAdd(&cs[col], rsum);
    }
    if (doCol) {
        __syncthreads();
        if (tid < 128) atomicAdd(&colsum[tid], cs[tid]);
    }
}

__global__ __launch_bounds__(128) void head_kernel(const float* __restrict__ colsum,
                                                   const float* __restrict__ w_head,
                                                   const float* __restrict__ b_head,
                                                   float* __restrict__ out) {
    __shared__ float pls[F];
    int t = threadIdx.x;
    float p = colsum[t] * (1.0f / (float)NN);
    pls[t] = p;
    out[NCLS + t] = p;
    __syncthreads();
    if (t < NCLS) {
        float sc = b_head[t];
        for (int f = 0; f < F; ++f) sc += pls[f] * w_head[f * NCLS + t];
        out[t] = sc;
    }
}

extern "C" void kernel_launch(void* const* d_in, const int* in_sizes, int n_in,
                              void* d_out, int out_size, void* d_ws, size_t ws_size,
                              hipStream_t stream) {
    const float* x       = (const float*)d_in[0];
    const int*   src     = (const int*)d_in[1];
    const int*   dst     = (const int*)d_in[2];
    const float* w_self0 = (const float*)d_in[3];
    const float* w_neigh0= (const float*)d_in[4];
    const float* b0      = (const float*)d_in[5];
    const float* w_self1 = (const float*)d_in[6];
    const float* w_neigh1= (const float*)d_in[7];
    const float* b1      = (const float*)d_in[8];
    const float* w_self2 = (const float*)d_in[9];
    const float* w_neigh2= (const float*)d_in[10];
    const float* b2      = (const float*)d_in[11];
    const float* w_head  = (const float*)d_in[12];
    const float* b_head  = (const float*)d_in[13];
    float* out = (float*)d_out;

    uint8_t* ws = (uint8_t*)d_ws;
    float* colsum   = (float*)(ws + OB_COLSUM);
    int*   bcur     = (int*)(ws + OB_BCUR);
    int*   row_start= (int*)(ws + OB_ROWSTART);
    float* inv_deg  = (float*)(ws + OB_INVDEG);
    uint32_t* pairs = (uint32_t*)(ws + OB_PAIRS);
    unsigned short* srcs16 = (unsigned short*)(ws + OB_SRCS16);
    uint8_t* wt     = ws + OB_WT;
    uint8_t* xb     = ws + OB_XB;     // bf16 L; doubles as hb2
    uint8_t* hb1    = ws + OB_HB1;
    uint8_t* x8     = ws + OB_X8;     // fp8; doubles as f8b
    uint8_t* f8a    = ws + OB_F8A;
    uint8_t* nb     = ws + OB_NB;

    // zero colsum + bucket fill counters
    hipMemsetAsync(d_ws, 0, 1536, stream);

    fused_prep<<<NB + PW_BLKS + CV_BLKS, 256, 0, stream>>>(
        x, xb, x8, w_self0, w_neigh0, w_self1, w_neigh1, w_self2, w_neigh2, wt,
        src, dst, bcur, pairs);
    pass_b<<<NB, 256, 0, stream>>>(pairs, bcur, row_start, inv_deg, srcs16);

    const int GB = (NN + 63) / 64;   // 782

    // layer 0: (xb, x8) -> (hb1, f8a)
    aggregate_f8<<<12500, 256, 0, stream>>>(x8, row_start, srcs16, inv_deg, nb);
    gemm_mfma<<<GB, 256, 0, stream>>>(xb, nb, wt + 0 * 32768, wt + 1 * 32768, b0,
                                      hb1, f8a, nullptr);
    // layer 1: (hb1, f8a) -> (xb, x8 as f8b)
    aggregate_f8<<<12500, 256, 0, stream>>>(f8a, row_start, srcs16, inv_deg, nb);
    gemm_mfma<<<GB, 256, 0, stream>>>(hb1, nb, wt + 2 * 32768, wt + 3 * 32768, b1,
                                      xb, x8, nullptr);
    // layer 2: (xb, x8) -> hb1, fused colsum, no f8 output
    aggregate_f8<<<12500, 256, 0, stream>>>(x8, row_start, srcs16, inv_deg, nb);
    gemm_mfma<<<GB, 256, 0, stream>>>(xb, nb, wt + 4 * 32768, wt + 5 * 32768, b2,
                                      hb1, nullptr, colsum);

    head_kernel<<<1, 128, 0, stream>>>(colsum, w_head, b_head, out);
}

// Round 9
// 186.701 us; speedup vs baseline: 1.0942x; 1.0942x over previous
//
#include <hip/hip_runtime.h>
#include <hip/hip_bf16.h>
#include <hip/hip_fp8.h>
#include <stdint.h>

#define NN 50000
#define NE 800000
#define F 128
#define NCLS 16
#define NB 196          // ceil(50000/256) buckets
#define BCAP 5120       // per-bucket capacity: mean 4096 + 16 sigma
#define PA_EPT 16       // edges per thread in pass_a part
#define PW_BLKS 192     // 6 matrices x 32 blocks
#define CV_BLKS 6250    // NN*32/256

typedef __attribute__((ext_vector_type(8))) short short8;
typedef __attribute__((ext_vector_type(4))) float f32x4;
typedef __attribute__((ext_vector_type(2))) float f32x2;
typedef __attribute__((ext_vector_type(4))) unsigned int uint4v;

// ---- ws byte offsets (ws_size ~256 MiB, plenty) ----
#define OB_COLSUM    0u          // float[128]
#define OB_BCUR      512u        // int[196] (fill counters, memset 0)
#define OB_ROWSTART  4096u       // int[50001]
#define OB_INVDEG    204800u     // float[50000]
#define OB_PAIRS     409600u     // u32[196*5120]
#define OB_SRCS16    4423680u    // u16[800000]
#define OB_WT        6023680u    // bf16 6*16384 (layout L)
#define OB_XB        6220800u    // bf16 [NN][128] layout L (doubles as HB2)
#define OB_HB1       19020800u   // bf16 [NN][128] layout L
#define OB_X8        31820800u   // fp8 [NN][128] row-major (doubles as F8B)
#define OB_F8A       38220800u   // fp8 [NN][128] row-major
#define OB_NB        44620800u   // bf16 [NN][128] layout L   ends ~57.4MB

// ---- swizzled bf16 feature layout L ----
// element (row,k) at byte: row*256 + 16*(chunk(k) ^ (row&15)) + inchunk(k)
// chunk(k) = (k>>5)*4 | ((k>>2)&3); inchunk = ((k>>4)&1)*8 + (k&3)*2
__device__ __forceinline__ uint32_t swz_off(uint32_t row, uint32_t k) {
    uint32_t c = ((k >> 5) << 2) | ((k >> 2) & 3u);
    uint32_t b = (((k >> 4) & 1u) << 3) | ((k & 3u) << 1);
    return (row << 8) + (((c ^ (row & 15u)) << 4) | b);
}

__device__ __forceinline__ uint32_t pack_bf2(float a, float b) {
    __hip_bfloat16 l = __float2bfloat16(a), h = __float2bfloat16(b);
    return ((uint32_t)(*(uint16_t*)&h) << 16) | (uint32_t)(*(uint16_t*)&l);
}

__device__ __forceinline__ uint8_t f32_to_fp8(float v) {
#if __has_builtin(__builtin_amdgcn_cvt_pk_fp8_f32)
    return (uint8_t)(__builtin_amdgcn_cvt_pk_fp8_f32(v, 0.f, 0, false) & 0xff);
#else
    __hip_fp8_e4m3 t(v);
    return t.__x;
#endif
}

__device__ __forceinline__ uint32_t f32x4_to_fp8x4(float a, float b, float c, float d) {
#if __has_builtin(__builtin_amdgcn_cvt_pk_fp8_f32)
    int r = __builtin_amdgcn_cvt_pk_fp8_f32(a, b, 0, false);
    r = __builtin_amdgcn_cvt_pk_fp8_f32(c, d, r, true);
    return (uint32_t)r;
#else
    __hip_fp8_e4m3 ta(a), tb(b), tc(c), td(d);
    return (uint32_t)ta.__x | ((uint32_t)tb.__x << 8) | ((uint32_t)tc.__x << 16) | ((uint32_t)td.__x << 24);
#endif
}

// accumulate 4 fp8 (one dword) into two packed-f32 accumulators
__device__ __forceinline__ void acc4(uint32_t d, f32x2& p0, f32x2& p1) {
#if __has_builtin(__builtin_amdgcn_cvt_pk_f32_fp8)
    p0 += __builtin_amdgcn_cvt_pk_f32_fp8((int)d, false);
    p1 += __builtin_amdgcn_cvt_pk_f32_fp8((int)d, true);
#else
    __hip_fp8_e4m3 t0, t1, t2, t3;
    t0.__x = (uint8_t)(d & 0xff); t1.__x = (uint8_t)((d >> 8) & 0xff);
    t2.__x = (uint8_t)((d >> 16) & 0xff); t3.__x = (uint8_t)((d >> 24) & 0xff);
    p0.x += (float)t0; p0.y += (float)t1; p1.x += (float)t2; p1.y += (float)t3;
#endif
}

// async global->LDS, 16B per lane (dest must be wave-uniform base + lane*16)
__device__ __forceinline__ void gload16(const void* g, void* l) {
    __builtin_amdgcn_global_load_lds(
        (const __attribute__((address_space(1))) unsigned int*)g,
        (__attribute__((address_space(3))) unsigned int*)l, 16, 0, 0);
}

// ====== fused prep: pass_a (196) | prep_w (192) | convert_x2 (6250) ======
__global__ __launch_bounds__(256) void fused_prep(
        const float* __restrict__ x, uint8_t* __restrict__ xb, uint8_t* __restrict__ x8,
        const float* __restrict__ w0, const float* __restrict__ w1,
        const float* __restrict__ w2, const float* __restrict__ w3,
        const float* __restrict__ w4, const float* __restrict__ w5,
        uint8_t* __restrict__ wt,
        const int* __restrict__ src, const int* __restrict__ dst,
        int* __restrict__ bcur, uint32_t* __restrict__ pairs) {
    __shared__ int cnt[NB];
    __shared__ int base_s[NB];
    int bid = blockIdx.x;
    int t = threadIdx.x;

    if (bid < NB) {
        for (int i = t; i < NB; i += 256) cnt[i] = 0;
        __syncthreads();
        uint32_t pk[PA_EPT];
        int bk[PA_EPT];
        int e0 = bid * (256 * PA_EPT) + t;
#pragma unroll
        for (int j = 0; j < PA_EPT; ++j) {
            int e = e0 + j * 256;
            if (e < NE) {
                int sv = src[e], dv = dst[e];
                bk[j] = dv >> 8;
                pk[j] = (uint32_t)sv | (((uint32_t)dv & 255u) << 16);
                atomicAdd(&cnt[bk[j]], 1);
            } else bk[j] = -1;
        }
        __syncthreads();
        for (int i = t; i < NB; i += 256) {
            if (cnt[i] > 0) base_s[i] = i * BCAP + atomicAdd(&bcur[i], cnt[i]);
            cnt[i] = 0;   // reuse as local cursor
        }
        __syncthreads();
#pragma unroll
        for (int j = 0; j < PA_EPT; ++j) {
            if (bk[j] >= 0) {
                int pos = base_s[bk[j]] + atomicAdd(&cnt[bk[j]], 1);
                pairs[pos] = pk[j];
            }
        }
        return;
    }
    bid -= NB;
    if (bid < PW_BLKS) {
        int m = bid >> 5;
        const float* w = m == 0 ? w0 : m == 1 ? w1 : m == 2 ? w2 : m == 3 ? w3 : m == 4 ? w4 : w5;
        int tt = (bid & 31) * 256 + t;          // 8192 pair-slots
        int n = tt >> 6;
        int k0 = (tt & 63) << 1;
        uint32_t pk = pack_bf2(w[k0 * F + n], w[(k0 + 1) * F + n]);
        *(uint32_t*)(wt + (uint32_t)m * 32768u + swz_off((uint32_t)n, (uint32_t)k0)) = pk;
        return;
    }
    bid -= PW_BLKS;
    int tt = bid * 256 + t;                     // NN*32 quad-slots
    uint32_t row = (uint32_t)tt >> 5;
    uint32_t q = (uint32_t)tt & 31u;            // 4-k group
    float4 v = *(const float4*)(x + row * F + q * 4);
    uint32_t c = ((q >> 3) << 2) | (q & 3u);
    uint32_t hi = (q >> 2) & 1u;
    uint2 pk;
    pk.x = pack_bf2(v.x, v.y);
    pk.y = pack_bf2(v.z, v.w);
    *(uint2*)(xb + (row << 8) + (((c ^ (row & 15u)) << 4) | (hi << 3))) = pk;
    *(uint32_t*)(x8 + row * 128u + q * 4u) = f32x4_to_fp8x4(v.x, v.y, v.z, v.w);
}

// ====== pass B: per-bucket count/scan (+inline bucket-base scan) ======
__global__ __launch_bounds__(256) void pass_b(const uint32_t* __restrict__ pairs,
                                              const int* __restrict__ bcur,   // fills
                                              int* __restrict__ row_start,
                                              float* __restrict__ inv_deg,
                                              unsigned short* __restrict__ srcs) {
    __shared__ int sarr[256];
    __shared__ int cnt[256];
    __shared__ int cur[256];
    int b = blockIdx.x, t = threadIdx.x;
    sarr[t] = (t < NB) ? bcur[t] : 0;
    __syncthreads();
    for (int off = 1; off < 256; off <<= 1) {
        int u = (t >= off) ? sarr[t - off] : 0;
        __syncthreads();
        sarr[t] += u;
        __syncthreads();
    }
    int fill = bcur[b];
    int out0 = sarr[b] - fill;   // exclusive prefix
    int in0 = b * BCAP;
    cnt[t] = 0;
    __syncthreads();
    for (int i = t; i < fill; i += 256)
        atomicAdd(&cnt[pairs[in0 + i] >> 16], 1);
    __syncthreads();
    int v = cnt[t];
    sarr[t] = v;
    __syncthreads();
    for (int off = 1; off < 256; off <<= 1) {
        int u = (t >= off) ? sarr[t - off] : 0;
        __syncthreads();
        sarr[t] += u;
        __syncthreads();
    }
    int excl = sarr[t] - v;
    cur[t] = out0 + excl;
    int row = (b << 8) + t;
    if (row < NN) {
        row_start[row] = out0 + excl;
        inv_deg[row] = 1.0f / (float)(v > 1 ? v : 1);
    }
    if (b == 0 && t == 0) row_start[NN] = NE;
    __syncthreads();
    for (int i = t; i < fill; i += 256) {
        uint32_t p = pairs[in0 + i];
        int pos = atomicAdd(&cur[p >> 16], 1);
        srcs[pos] = (unsigned short)(p & 0xffffu);
    }
}

// ====== aggregate: wave/node, 8 lanes x dwordx4 per row -> 8 edges/instr ======
__global__ __launch_bounds__(256) void aggregate_f8(
        const uint8_t* __restrict__ hf8, const int* __restrict__ row_start,
        const unsigned short* __restrict__ srcs, const float* __restrict__ inv_deg,
        uint8_t* __restrict__ nb) {
    int node = blockIdx.x * 4 + (threadIdx.x >> 6);
    int l = threadIdx.x & 63;
    int g = l >> 3;                          // edge slot 0..7
    uint32_t m = (uint32_t)(l & 7);          // feats [16m, 16m+16)
    const uint8_t* base = hf8 + m * 16u;
    int e0 = row_start[node], e1 = row_start[node + 1];
    f32x2 a[8];
#pragma unroll
    for (int i = 0; i < 8; ++i) { a[i].x = 0.f; a[i].y = 0.f; }

    int e = e0;
    for (; e + 32 <= e1; e += 32) {          // 32 edges in flight per wave
        uint32_t s0 = srcs[e + g];
        uint32_t s1 = srcs[e + 8 + g];
        uint32_t s2 = srcs[e + 16 + g];
        uint32_t s3 = srcs[e + 24 + g];
        uint4 d0 = *(const uint4*)(base + (s0 << 7));
        uint4 d1 = *(const uint4*)(base + (s1 << 7));
        uint4 d2 = *(const uint4*)(base + (s2 << 7));
        uint4 d3 = *(const uint4*)(base + (s3 << 7));
        acc4(d0.x, a[0], a[1]); acc4(d0.y, a[2], a[3]);
        acc4(d0.z, a[4], a[5]); acc4(d0.w, a[6], a[7]);
        acc4(d1.x, a[0], a[1]); acc4(d1.y, a[2], a[3]);
        acc4(d1.z, a[4], a[5]); acc4(d1.w, a[6], a[7]);
        acc4(d2.x, a[0], a[1]); acc4(d2.y, a[2], a[3]);
        acc4(d2.z, a[4], a[5]); acc4(d2.w, a[6], a[7]);
        acc4(d3.x, a[0], a[1]); acc4(d3.y, a[2], a[3]);
        acc4(d3.z, a[4], a[5]); acc4(d3.w, a[6], a[7]);
    }
    for (; e + 8 <= e1; e += 8) {
        uint32_t sa = srcs[e + g];
        uint4 da = *(const uint4*)(base + (sa << 7));
        acc4(da.x, a[0], a[1]); acc4(da.y, a[2], a[3]);
        acc4(da.z, a[4], a[5]); acc4(da.w, a[6], a[7]);
    }
    if (e + g < e1) {                        // predicated 0..7-edge tail
        uint32_t sa = srcs[e + g];
        uint4 da = *(const uint4*)(base + (sa << 7));
        acc4(da.x, a[0], a[1]); acc4(da.y, a[2], a[3]);
        acc4(da.z, a[4], a[5]); acc4(da.w, a[6], a[7]);
    }
    // combine 8 edge groups: xor 8, 16, 32
#pragma unroll
    for (int d = 8; d < 64; d <<= 1) {
#pragma unroll
        for (int i = 0; i < 8; ++i) {
            a[i].x += __shfl_xor(a[i].x, d);
            a[i].y += __shfl_xor(a[i].y, d);
        }
    }
    if (g == 0) {
        float idg = inv_deg[node];
        uint32_t rx = (uint32_t)node & 15u;
        char* rowp = (char*)nb + ((uint32_t)node << 8);
        uint32_t bh = (m & 1u) << 3;
#pragma unroll
        for (int jj = 0; jj < 4; ++jj) {
            uint32_t c = ((m >> 1) << 2) | (uint32_t)jj;
            uint2 w;
            w.x = pack_bf2(a[2 * jj].x * idg, a[2 * jj].y * idg);
            w.y = pack_bf2(a[2 * jj + 1].x * idg, a[2 * jj + 1].y * idg);
            *(uint2*)(rowp + (((c ^ rx) << 4) | bh)) = w;
        }
    }
}

// ====== MFMA GEMM (128 rows/block): relu(As@Ws + An@Wn + b); f8 mirror ======
__global__ __launch_bounds__(256) void gemm_mfma(
        const uint8_t* __restrict__ a_self, const uint8_t* __restrict__ a_neigh,
        const uint8_t* __restrict__ wt_self, const uint8_t* __restrict__ wt_neigh,
        const float* __restrict__ bias, uint8_t* __restrict__ hout,
        uint8_t* hout_f8, float* colsum) {
    __shared__ uint4v As4[2048];   // 32 KB: 128 rows layout L
    __shared__ uint4v Ws4[2048];   // 32 KB
    __shared__ float cs[128];
    int tid = threadIdx.x;
    int lane = tid & 63, wave = tid >> 6;
    int rl = lane & 15, g = lane >> 4;
    int row0 = blockIdx.x * 128;

    f32x4 acc[2][8];
    f32x4 z = {0.f, 0.f, 0.f, 0.f};
#pragma unroll
    for (int rt = 0; rt < 2; ++rt)
#pragma unroll
        for (int nt = 0; nt < 8; ++nt) acc[rt][nt] = z;

    const char* AsB = (const char*)As4;
    const char* WsB = (const char*)Ws4;

#pragma unroll
    for (int pass = 0; pass < 2; ++pass) {
        if (pass) __syncthreads();
        const uint4v* ga = (const uint4v*)((pass ? a_neigh : a_self) + (size_t)row0 * 256);
        const uint4v* gw = (const uint4v*)(pass ? wt_neigh : wt_self);
#pragma unroll
        for (int i = 0; i < 8; ++i) gload16(&ga[tid + i * 256], &As4[tid + i * 256]);
#pragma unroll
        for (int i = 0; i < 8; ++i) gload16(&gw[tid + i * 256], &Ws4[tid + i * 256]);
        __syncthreads();
#pragma unroll
        for (int ks = 0; ks < 4; ++ks) {
            int chunk = ((ks << 2) | g) ^ rl;
#pragma unroll
            for (int rt = 0; rt < 2; ++rt) {
                short8 a = *(const short8*)(AsB + ((wave * 32 + rt * 16 + rl) << 8) + (chunk << 4));
#pragma unroll
                for (int nt = 0; nt < 8; ++nt) {
                    short8 bb = *(const short8*)(WsB + ((nt * 16 + rl) << 8) + (chunk << 4));
                    acc[rt][nt] = __builtin_amdgcn_mfma_f32_16x16x32_bf16(a, bb, acc[rt][nt], 0, 0, 0);
                }
            }
        }
    }

    bool doCol = (colsum != nullptr);
    bool doF8 = (hout_f8 != nullptr);
    if (doCol) {
        if (tid < 128) cs[tid] = 0.f;
        __syncthreads();
    }
#pragma unroll
    for (int rt = 0; rt < 2; ++rt) {
#pragma unroll
        for (int nt = 0; nt < 8; ++nt) {
            int col = nt * 16 + rl;
            float bv = bias[col];
            float rsum = 0.f;
#pragma unroll
            for (int i = 0; i < 4; ++i) {
                int row = row0 + wave * 32 + rt * 16 + g * 4 + i;
                if (row < NN) {
                    float v = fmaxf(acc[rt][nt][i] + bv, 0.f);
                    rsum += v;
                    *(__hip_bfloat16*)(hout + swz_off((uint32_t)row, (uint32_t)col)) =
                        __float2bfloat16(v);
                    if (doF8) hout_f8[(uint32_t)row * 128u + (uint32_t)col] = f32_to_fp8(v);
                }
            }
            if (doCol) atomicAdd(&cs[col], rsum);
        }
    }
    if (doCol) {
        __syncthreads();
        if (tid < 128) atomicAdd(&colsum[tid], cs[tid]);
    }
}

__global__ __launch_bounds__(128) void head_kernel(const float* __restrict__ colsum,
                                                   const float* __restrict__ w_head,
                                                   const float* __restrict__ b_head,
                                                   float* __restrict__ out) {
    __shared__ float pls[F];
    int t = threadIdx.x;
    float p = colsum[t] * (1.0f / (float)NN);
    pls[t] = p;
    out[NCLS + t] = p;
    __syncthreads();
    if (t < NCLS) {
        float sc = b_head[t];
        for (int f = 0; f < F; ++f) sc += pls[f] * w_head[f * NCLS + t];
        out[t] = sc;
    }
}

extern "C" void kernel_launch(void* const* d_in, const int* in_sizes, int n_in,
                              void* d_out, int out_size, void* d_ws, size_t ws_size,
                              hipStream_t stream) {
    const float* x       = (const float*)d_in[0];
    const int*   src     = (const int*)d_in[1];
    const int*   dst     = (const int*)d_in[2];
    const float* w_self0 = (const float*)d_in[3];
    const float* w_neigh0= (const float*)d_in[4];
    const float* b0      = (const float*)d_in[5];
    const float* w_self1 = (const float*)d_in[6];
    const float* w_neigh1= (const float*)d_in[7];
    const float* b1      = (const float*)d_in[8];
    const float* w_self2 = (const float*)d_in[9];
    const float* w_neigh2= (const float*)d_in[10];
    const float* b2      = (const float*)d_in[11];
    const float* w_head  = (const float*)d_in[12];
    const float* b_head  = (const float*)d_in[13];
    float* out = (float*)d_out;

    uint8_t* ws = (uint8_t*)d_ws;
    float* colsum   = (float*)(ws + OB_COLSUM);
    int*   bcur     = (int*)(ws + OB_BCUR);
    int*   row_start= (int*)(ws + OB_ROWSTART);
    float* inv_deg  = (float*)(ws + OB_INVDEG);
    uint32_t* pairs = (uint32_t*)(ws + OB_PAIRS);
    unsigned short* srcs16 = (unsigned short*)(ws + OB_SRCS16);
    uint8_t* wt     = ws + OB_WT;
    uint8_t* xb     = ws + OB_XB;     // bf16 L; doubles as hb2
    uint8_t* hb1    = ws + OB_HB1;
    uint8_t* x8     = ws + OB_X8;     // fp8; doubles as f8b
    uint8_t* f8a    = ws + OB_F8A;
    uint8_t* nb     = ws + OB_NB;

    // zero colsum + bucket fill counters
    hipMemsetAsync(d_ws, 0, 1536, stream);

    fused_prep<<<NB + PW_BLKS + CV_BLKS, 256, 0, stream>>>(
        x, xb, x8, w_self0, w_neigh0, w_self1, w_neigh1, w_self2, w_neigh2, wt,
        src, dst, bcur, pairs);
    pass_b<<<NB, 256, 0, stream>>>(pairs, bcur, row_start, inv_deg, srcs16);

    const int GB = (NN + 127) / 128;   // 391

    // layer 0: (xb, x8) -> (hb1, f8a)
    aggregate_f8<<<12500, 256, 0, stream>>>(x8, row_start, srcs16, inv_deg, nb);
    gemm_mfma<<<GB, 256, 0, stream>>>(xb, nb, wt + 0 * 32768, wt + 1 * 32768, b0,
                                      hb1, f8a, nullptr);
    // layer 1: (hb1, f8a) -> (xb, x8 as f8b)
    aggregate_f8<<<12500, 256, 0, stream>>>(f8a, row_start, srcs16, inv_deg, nb);
    gemm_mfma<<<GB, 256, 0, stream>>>(hb1, nb, wt + 2 * 32768, wt + 3 * 32768, b1,
                                      xb, x8, nullptr);
    // layer 2: (xb, x8) -> hb1, fused colsum, no f8 output
    aggregate_f8<<<12500, 256, 0, stream>>>(x8, row_start, srcs16, inv_deg, nb);
    gemm_mfma<<<GB, 256, 0, stream>>>(xb, nb, wt + 4 * 32768, wt + 5 * 32768, b2,
                                      hb1, nullptr, colsum);

    head_kernel<<<1, 128, 0, stream>>>(colsum, w_head, b_head, out);
}